// Round 3
// baseline (324.280 us; speedup 1.0000x reference)
//
#include <hip/hip_runtime.h>
#include <hip/hip_bf16.h>

// LowRankSoftmaxAttentionBlock round 3:
//  k_attn rewritten: 8 waves x 32 Q rows (256/block), KV split 2, grid 256.
//  Double-buffered LDS staging via global_load_lds (linear dest, inverse-swizzled
//  global source), counted vmcnt(8), raw s_barrier + sched_barrier fences.
//  Unnormalized partials + den folded into k_outln (unchanged from r2).
// MFMA: v_mfma_f32_16x16x32_bf16. A/B frag: own-idx = lane&15, k = (lane>>4)*8+j.
// C/D: col = lane&15, row = (lane>>4)*4 + reg.

typedef __bf16 bf16;
typedef __bf16 v8bf __attribute__((ext_vector_type(8)));
typedef __bf16 v4bf __attribute__((ext_vector_type(4)));
typedef float  v4f  __attribute__((ext_vector_type(4)));

#define MFMA(a,b,c) __builtin_amdgcn_mfma_f32_16x16x32_bf16((a),(b),(c),0,0,0)

// ---------------- K0: convert weights to bf16 ----------------
__global__ __launch_bounds__(256) void k_prep(const float* __restrict__ wq, const float* __restrict__ wk,
                       const float* __restrict__ wv, const float* __restrict__ wo,
                       const float* __restrict__ E,  const float* __restrict__ F,
                       bf16* __restrict__ wqkv, bf16* __restrict__ wob,
                       bf16* __restrict__ ebf,  bf16* __restrict__ fbf){
  int i = blockIdx.x * 256 + threadIdx.x;          // 0..196607
  float v;
  if (i < 65536)       v = wq[i];
  else if (i < 131072) v = wk[i - 65536];
  else                 v = wv[i - 131072];
  wqkv[i] = (bf16)v;
  if (i < 65536) wob[i] = (bf16)wo[i];
  if (i < 8192) { ebf[i] = (bf16)E[i]; fbf[i] = (bf16)F[i]; }
}

// ---------------- K1: LayerNorm1 -> tn (bf16) ----------------
__global__ __launch_bounds__(256) void k_ln1(const float* __restrict__ tok, const float* __restrict__ g1,
                      const float* __restrict__ b1, bf16* __restrict__ tn){
  int row  = blockIdx.x * 4 + (threadIdx.x >> 6);
  int lane = threadIdx.x & 63;
  float4 x = *reinterpret_cast<const float4*>(tok + (size_t)row * 256 + lane * 4);
  float s  = x.x + x.y + x.z + x.w;
  float ss = x.x*x.x + x.y*x.y + x.z*x.z + x.w*x.w;
  for (int o = 1; o < 64; o <<= 1) { s += __shfl_xor(s, o); ss += __shfl_xor(ss, o); }
  float mean = s * (1.0f/256.0f);
  float var  = ss * (1.0f/256.0f) - mean*mean;
  float inv  = rsqrtf(var + 1e-5f);
  float4 g  = *reinterpret_cast<const float4*>(g1 + lane*4);
  float4 bb = *reinterpret_cast<const float4*>(b1 + lane*4);
  v4bf o4;
  o4[0] = (bf16)((x.x-mean)*inv*g.x + bb.x);
  o4[1] = (bf16)((x.y-mean)*inv*g.y + bb.y);
  o4[2] = (bf16)((x.z-mean)*inv*g.z + bb.z);
  o4[3] = (bf16)((x.w-mean)*inv*g.w + bb.w);
  *reinterpret_cast<v4bf*>(tn + (size_t)row * 256 + lane * 4) = o4;
}

// ---------------- K2: QKV GEMM + fused l2norm; Q row-major, K/V transposed ----------------
__global__ __launch_bounds__(512) void k_qkv(const bf16* __restrict__ tn, const bf16* __restrict__ w,
                                             bf16* __restrict__ Qn, bf16* __restrict__ kT,
                                             bf16* __restrict__ vT){
  __shared__ float ssL[2][4][64];
  int bm = blockIdx.x, seg = blockIdx.y;
  int wid = threadIdx.x >> 6, lane = threadIdx.x & 63;
  int wr = wid >> 2, wc = wid & 3;
  int row0 = bm * 128 + wr * 64;
  int col0 = wc * 64;
  int lr = lane & 15, lg = lane >> 4;
  const bf16* wseg = w + (size_t)seg * 65536;
  v4f acc[4][4] = {};
  for (int k0 = 0; k0 < 256; k0 += 32) {
    v8bf a[4], b[4];
#pragma unroll
    for (int mi = 0; mi < 4; mi++)
      a[mi] = *reinterpret_cast<const v8bf*>(tn + (size_t)(row0 + mi*16 + lr) * 256 + k0 + lg*8);
#pragma unroll
    for (int ni = 0; ni < 4; ni++)
      b[ni] = *reinterpret_cast<const v8bf*>(wseg + (size_t)(col0 + ni*16 + lr) * 256 + k0 + lg*8);
#pragma unroll
    for (int mi = 0; mi < 4; mi++)
#pragma unroll
      for (int ni = 0; ni < 4; ni++)
        acc[mi][ni] = MFMA(a[mi], b[ni], acc[mi][ni]);
  }
  if (seg < 2) {   // row l2norm across the 4 wc waves
#pragma unroll
    for (int mi = 0; mi < 4; mi++)
#pragma unroll
      for (int q = 0; q < 4; q++) {
        float s = acc[mi][0][q]*acc[mi][0][q] + acc[mi][1][q]*acc[mi][1][q]
                + acc[mi][2][q]*acc[mi][2][q] + acc[mi][3][q]*acc[mi][3][q];
        s += __shfl_xor(s, 1); s += __shfl_xor(s, 2); s += __shfl_xor(s, 4); s += __shfl_xor(s, 8);
        if (lr == 0) ssL[wr][wc][mi*16 + lg*4 + q] = s;
      }
    __syncthreads();
#pragma unroll
    for (int mi = 0; mi < 4; mi++)
#pragma unroll
      for (int q = 0; q < 4; q++) {
        int idx = mi*16 + lg*4 + q;
        float tot = ssL[wr][0][idx] + ssL[wr][1][idx] + ssL[wr][2][idx] + ssL[wr][3][idx];
        float inv = rsqrtf(fmaxf(tot, 1e-24f));
#pragma unroll
        for (int ni = 0; ni < 4; ni++) acc[mi][ni][q] *= inv;
      }
  }
  if (seg == 0) {
#pragma unroll
    for (int mi = 0; mi < 4; mi++)
#pragma unroll
      for (int ni = 0; ni < 4; ni++)
#pragma unroll
        for (int q = 0; q < 4; q++)
          Qn[(size_t)(row0 + mi*16 + lg*4 + q) * 256 + col0 + ni*16 + lr] = (bf16)acc[mi][ni][q];
  } else {
    bf16* dst = (seg == 1) ? kT : vT;
    int batch = row0 >> 12;
    int nloc  = row0 & 4095;
#pragma unroll
    for (int mi = 0; mi < 4; mi++)
#pragma unroll
      for (int ni = 0; ni < 4; ni++) {
        v4bf o4;
        o4[0]=(bf16)acc[mi][ni][0]; o4[1]=(bf16)acc[mi][ni][1];
        o4[2]=(bf16)acc[mi][ni][2]; o4[3]=(bf16)acc[mi][ni][3];
        *reinterpret_cast<v4bf*>(dst + ((size_t)batch*256 + col0 + ni*16 + lr) * 4096
                                     + nloc + mi*16 + lg*4) = o4;
      }
  }
}

// ---------------- K4a: kp[b][k=2048][h=256] = E @ K_blk, from kT[b][h][n] ----------------
__global__ __launch_bounds__(256) void k_kproj(const bf16* __restrict__ kT, const bf16* __restrict__ ebf,
                                               bf16* __restrict__ kp){
  int b = blockIdx.x >> 5, blk = blockIdx.x & 31;
  int w = threadIdx.x >> 6, lane = threadIdx.x & 63;
  int lr = lane & 15, lg = lane >> 4;
  const bf16* kb = kT + (size_t)b * 256 * 4096 + blk * 128;
  v8bf a[4][4];
#pragma unroll
  for (int kt = 0; kt < 4; kt++)
#pragma unroll
    for (int sc = 0; sc < 4; sc++)
      a[kt][sc] = *reinterpret_cast<const v8bf*>(ebf + (size_t)(kt*16 + lr) * 128 + sc*32 + lg*8);
  v4f acc[4][4] = {};
#pragma unroll
  for (int nt = 0; nt < 4; nt++) {
    int ht = w*4 + nt;
#pragma unroll
    for (int sc = 0; sc < 4; sc++) {
      v8bf bfrag = *reinterpret_cast<const v8bf*>(kb + (size_t)(ht*16 + lr) * 4096 + sc*32 + lg*8);
#pragma unroll
      for (int kt = 0; kt < 4; kt++)
        acc[kt][nt] = MFMA(a[kt][sc], bfrag, acc[kt][nt]);
    }
  }
#pragma unroll
  for (int kt = 0; kt < 4; kt++)
#pragma unroll
    for (int nt = 0; nt < 4; nt++)
#pragma unroll
      for (int q = 0; q < 4; q++)
        kp[(size_t)(b*2048 + blk*64 + kt*16 + lg*4 + q) * 256 + w*64 + nt*16 + lr] = (bf16)acc[kt][nt][q];
}

// ---------------- K4b: vpt[b][h=256][k=2048] = (F @ V_blk)^T, from vT[b][h][n] ----------------
__global__ __launch_bounds__(256) void k_vproj(const bf16* __restrict__ vT, const bf16* __restrict__ fbf,
                                               bf16* __restrict__ vpt){
  int b = blockIdx.x >> 5, blk = blockIdx.x & 31;
  int w = threadIdx.x >> 6, lane = threadIdx.x & 63;
  int lr = lane & 15, lg = lane >> 4;
  const bf16* vb = vT + (size_t)b * 256 * 4096 + blk * 128;
  v8bf a[4][4];
#pragma unroll
  for (int kt = 0; kt < 4; kt++)
#pragma unroll
    for (int sc = 0; sc < 4; sc++)
      a[kt][sc] = *reinterpret_cast<const v8bf*>(fbf + (size_t)(kt*16 + lr) * 128 + sc*32 + lg*8);
  v4f acc[4][4] = {};   // [nt][kt]
#pragma unroll
  for (int nt = 0; nt < 4; nt++) {
    int ht = w*4 + nt;
#pragma unroll
    for (int sc = 0; sc < 4; sc++) {
      v8bf bfrag = *reinterpret_cast<const v8bf*>(vb + (size_t)(ht*16 + lr) * 4096 + sc*32 + lg*8);
#pragma unroll
      for (int kt = 0; kt < 4; kt++)
        acc[nt][kt] = MFMA(a[kt][sc], bfrag, acc[nt][kt]);
    }
  }
#pragma unroll
  for (int nt = 0; nt < 4; nt++)
#pragma unroll
    for (int kt = 0; kt < 4; kt++) {
      v4bf o4;
      o4[0]=(bf16)acc[nt][kt][0]; o4[1]=(bf16)acc[nt][kt][1];
      o4[2]=(bf16)acc[nt][kt][2]; o4[3]=(bf16)acc[nt][kt][3];
      *reinterpret_cast<v4bf*>(vpt + ((size_t)b*256 + w*64 + nt*16 + lr) * 2048
                                   + blk*64 + kt*16 + lg*4) = o4;
    }
}

// ---------------- K5: attention v3 ----------------
// grid 256: b = bid&7 (XCD affinity), mb = (bid>>3)&15, half = bid>>7.
// block 512 = 8 waves x 32 Q rows. KV 1024 per block = 16 chunks of 64.
// LDS: Ks dbuf 2x32KB + Vs dbuf 2x32KB + Ps 32KB = 160 KiB.
__global__ __launch_bounds__(512, 2) void k_attn(const bf16* __restrict__ Qn, const bf16* __restrict__ kp,
                                              const bf16* __restrict__ vpt, const float* __restrict__ scalep,
                                              bf16* __restrict__ attnP, float* __restrict__ denP){
  __shared__ __align__(16) bf16 Ks[2][64 * 256];   // [row r][unit u]: unit holds global cols (u^(r&7))*8..+7
  __shared__ __align__(16) bf16 Vs[2][256 * 64];   // [row h][unit u]: unit holds global kv (u^(h&7))*8..+7
  __shared__ __align__(16) bf16 Ps[8][32 * 64];    // per-wave P, XOR-swizzled 16B units
  int bid = blockIdx.x;
  int b = bid & 7, mb = (bid >> 3) & 15, half = bid >> 7;
  int w = threadIdx.x >> 6, lane = threadIdx.x & 63;
  int lr = lane & 15, lg = lane >> 4;
  int m0g = b*4096 + mb*256 + w*32;
  int kc0 = half * 1024;
  float scv = scalep[0];
  float sscale = ((scv > 20.f) ? scv : log1pf(__expf(scv))) * 0.0625f; // softplus/sqrt(256)
  const bf16* kpb = kp  + (size_t)b * 2048 * 256;
  const bf16* vpb = vpt + (size_t)b * 256 * 2048;
  bf16* Pw = &Ps[w][0];

  // Q fragments: 2 mtiles x 8 ksteps
  v8bf q[2][8];
#pragma unroll
  for (int mt = 0; mt < 2; mt++)
#pragma unroll
    for (int kk = 0; kk < 8; kk++)
      q[mt][kk] = *reinterpret_cast<const v8bf*>(Qn + (size_t)(m0g + mt*16 + lr) * 256 + kk*32 + lg*8);

  // staging source offsets (elements), per lane, inverse-swizzled
  int kOff0[4], vOff0[4];
#pragma unroll
  for (int s2 = 0; s2 < 4; s2++) {
    int seg = w*4 + s2;
    int kr = seg*2 + (lane >> 5);                 // 0..63
    int ku = (lane & 31) ^ (kr & 7);
    kOff0[s2] = (kc0 + kr) * 256 + ku * 8;
    int vr = seg*8 + (lane >> 3);                 // 0..255
    int vu = (lane & 7) ^ (vr & 7);
    vOff0[s2] = vr * 2048 + kc0 + vu * 8;
  }

  v4f o[2][16] = {};
  float den[2][4] = {};

  auto STAGE = [&](int buf, int t) {
    int kAdv = t * 16384, vAdv = t * 64;
#pragma unroll
    for (int s2 = 0; s2 < 4; s2++)
      __builtin_amdgcn_global_load_lds(
        (const __attribute__((address_space(1))) void*)(kpb + kOff0[s2] + kAdv),
        (__attribute__((address_space(3))) void*)&Ks[buf][(w*4 + s2) * 512], 16, 0, 0);
#pragma unroll
    for (int s2 = 0; s2 < 4; s2++)
      __builtin_amdgcn_global_load_lds(
        (const __attribute__((address_space(1))) void*)(vpb + vOff0[s2] + vAdv),
        (__attribute__((address_space(3))) void*)&Vs[buf][(w*4 + s2) * 512], 16, 0, 0);
  };

  auto COMPUTE = [&](int buf) {
    const bf16* Kb = &Ks[buf][0];
    const bf16* Vb = &Vs[buf][0];
    v4f s4[2][4] = {};
    __builtin_amdgcn_s_setprio(1);
#pragma unroll
    for (int kk = 0; kk < 8; kk++) {
      int csw = ((kk*4 + lg) ^ (lr & 7)) * 8;
#pragma unroll
      for (int n = 0; n < 4; n++) {
        v8bf bk = *reinterpret_cast<const v8bf*>(Kb + (n*16 + lr) * 256 + csw);
        s4[0][n] = MFMA(q[0][kk], bk, s4[0][n]);
        s4[1][n] = MFMA(q[1][kk], bk, s4[1][n]);
      }
    }
    __builtin_amdgcn_s_setprio(0);
#pragma unroll
    for (int mt = 0; mt < 2; mt++)
#pragma unroll
      for (int n = 0; n < 4; n++)
#pragma unroll
        for (int r = 0; r < 4; r++) {
          float p = __expf(s4[mt][n][r] * sscale);
          den[mt][r] += p;
          int row = mt*16 + lg*4 + r;
          Pw[row*64 + (((n*2 + (lr >> 3)) ^ (row & 7)) << 3) + (lr & 7)] = (bf16)p;
        }
    v8bf pa[2][2];
#pragma unroll
    for (int mt = 0; mt < 2; mt++)
#pragma unroll
      for (int c = 0; c < 2; c++) {
        int row = mt*16 + lr;
        pa[mt][c] = *reinterpret_cast<const v8bf*>(Pw + row*64 + (((c*4 + lg) ^ (row & 7)) << 3));
      }
    __builtin_amdgcn_s_setprio(1);
#pragma unroll
    for (int vc = 0; vc < 16; vc++) {
#pragma unroll
      for (int c = 0; c < 2; c++) {
        v8bf bv = *reinterpret_cast<const v8bf*>(Vb + (vc*16 + lr) * 64 + (((c*4 + lg) ^ (lr & 7)) << 3));
        o[0][vc] = MFMA(pa[0][c], bv, o[0][vc]);
        o[1][vc] = MFMA(pa[1][c], bv, o[1][vc]);
      }
    }
    __builtin_amdgcn_s_setprio(0);
  };

  STAGE(0, 0);
  int cur = 0;
  for (int t = 0; t < 15; t++) {
    STAGE(cur ^ 1, t + 1);
    asm volatile("s_waitcnt vmcnt(8)" ::: "memory");   // own chunk-t loads done
    __builtin_amdgcn_s_barrier();                      // all waves' loads done
    __builtin_amdgcn_sched_barrier(0);
    COMPUTE(cur);
    __builtin_amdgcn_sched_barrier(0);
    __builtin_amdgcn_s_barrier();                      // all waves done reading buf[cur]
    cur ^= 1;
  }
  asm volatile("s_waitcnt vmcnt(0)" ::: "memory");
  __builtin_amdgcn_s_barrier();
  __builtin_amdgcn_sched_barrier(0);
  COMPUTE(cur);

  // denominator partial: reduce over the 16 lr lanes (kv ≡ lr mod 16)
#pragma unroll
  for (int mt = 0; mt < 2; mt++)
#pragma unroll
    for (int r = 0; r < 4; r++) {
      float d = den[mt][r];
      d += __shfl_xor(d, 1); d += __shfl_xor(d, 2); d += __shfl_xor(d, 4); d += __shfl_xor(d, 8);
      den[mt][r] = d;
    }
  size_t obase = (size_t)half * 32768 * 256;
#pragma unroll
  for (int mt = 0; mt < 2; mt++)
#pragma unroll
    for (int vc = 0; vc < 16; vc++)
#pragma unroll
      for (int r = 0; r < 4; r++)
        attnP[obase + (size_t)(m0g + mt*16 + lg*4 + r) * 256 + vc*16 + lr] = (bf16)o[mt][vc][r];
  if (lr == 0) {
#pragma unroll
    for (int mt = 0; mt < 2; mt++)
#pragma unroll
      for (int r = 0; r < 4; r++)
        denP[half*32768 + m0g + mt*16 + lg*4 + r] = den[mt][r];
  }
}

// ---------------- K6: out = LN2(tokens + 0.1 * ((o0+o1)/(d0+d1)) @ Wo^T) ----------------
__global__ __launch_bounds__(256) void k_outln(const bf16* __restrict__ attnP, const float* __restrict__ denP,
                                               const bf16* __restrict__ wob, const float* __restrict__ tok,
                                               const float* __restrict__ g2, const float* __restrict__ b2,
                                               float* __restrict__ out){
  int w = threadIdx.x >> 6, lane = threadIdx.x & 63;
  int lr = lane & 15, lg = lane >> 4;
  int m0 = blockIdx.x * 64 + w * 16;
  v8bf a[8];
#pragma unroll
  for (int kk = 0; kk < 8; kk++) {
    v8bf x0 = *reinterpret_cast<const v8bf*>(attnP + (size_t)(m0 + lr) * 256 + kk*32 + lg*8);
    v8bf x1 = *reinterpret_cast<const v8bf*>(attnP + (size_t)32768*256 + (size_t)(m0 + lr) * 256 + kk*32 + lg*8);
#pragma unroll
    for (int j = 0; j < 8; j++) a[kk][j] = (bf16)((float)x0[j] + (float)x1[j]);
  }
  float dden[4];
#pragma unroll
  for (int r = 0; r < 4; r++) {
    int row = m0 + lg*4 + r;
    dden[r] = denP[row] + denP[32768 + row];
  }
  v4f acc[16] = {};
#pragma unroll
  for (int vc = 0; vc < 16; vc++)
#pragma unroll
    for (int kk = 0; kk < 8; kk++) {
      v8bf bv = *reinterpret_cast<const v8bf*>(wob + (size_t)(vc*16 + lr) * 256 + kk*32 + lg*8);
      acc[vc] = MFMA(a[kk], bv, acc[vc]);
    }
  float sum[4] = {0,0,0,0}, ssum[4] = {0,0,0,0};
#pragma unroll
  for (int vc = 0; vc < 16; vc++)
#pragma unroll
    for (int r = 0; r < 4; r++) {
      float t = tok[(size_t)(m0 + lg*4 + r) * 256 + vc*16 + lr];
      float x = t + 0.1f * (acc[vc][r] / dden[r]);
      acc[vc][r] = x;
      sum[r] += x; ssum[r] += x*x;
    }
#pragma unroll
  for (int r = 0; r < 4; r++) {
    float s_ = sum[r], q_ = ssum[r];
    s_ += __shfl_xor(s_, 1); s_ += __shfl_xor(s_, 2); s_ += __shfl_xor(s_, 4); s_ += __shfl_xor(s_, 8);
    q_ += __shfl_xor(q_, 1); q_ += __shfl_xor(q_, 2); q_ += __shfl_xor(q_, 4); q_ += __shfl_xor(q_, 8);
    sum[r] = s_ * (1.0f/256.0f); ssum[r] = q_ * (1.0f/256.0f);
  }
#pragma unroll
  for (int vc = 0; vc < 16; vc++) {
    float g = g2[vc*16 + lr], bb = b2[vc*16 + lr];
#pragma unroll
    for (int r = 0; r < 4; r++) {
      float mean = sum[r];
      float var  = ssum[r] - mean*mean;
      float inv  = rsqrtf(var + 1e-5f);
      out[(size_t)(m0 + lg*4 + r) * 256 + vc*16 + lr] = (acc[vc][r] - mean) * inv * g + bb;
    }
  }
}

// ---------------- launch ----------------
extern "C" void kernel_launch(void* const* d_in, const int* in_sizes, int n_in,
                              void* d_out, int out_size, void* d_ws, size_t ws_size,
                              hipStream_t stream){
  (void)in_sizes; (void)n_in; (void)out_size; (void)ws_size;
  const float* tok = (const float*)d_in[0];
  const float* wq  = (const float*)d_in[1];
  const float* wk  = (const float*)d_in[2];
  const float* wv  = (const float*)d_in[3];
  const float* wo  = (const float*)d_in[4];
  const float* E   = (const float*)d_in[5];
  const float* F   = (const float*)d_in[6];
  const float* g1  = (const float*)d_in[7];
  const float* b1  = (const float*)d_in[8];
  const float* g2  = (const float*)d_in[9];
  const float* b2  = (const float*)d_in[10];
  const float* sc  = (const float*)d_in[11];
  float* out = (float*)d_out;
  char* ws = (char*)d_ws;
  // ws layout (bytes), total 84,443,136
  bf16* tn   = (bf16*)(ws + 0);          // [32768][256]; dead after k_qkv -> denP
  bf16* Qn   = (bf16*)(ws + 16777216);   // [32768][256] normalized Q (live through k_attn)
  bf16* kT   = (bf16*)(ws + 33554432);   // [8][256][4096]; dead after k_kproj -> attnP
  bf16* vT   = (bf16*)(ws + 50331648);   // [8][256][4096]; dead after k_vproj -> attnP half1
  bf16* kp   = (bf16*)(ws + 67108864);   // [8][2048][256]
  bf16* vpt  = (bf16*)(ws + 75497472);   // [8][256][2048]
  bf16* wqkv = (bf16*)(ws + 83886080);   // [768][256]
  bf16* wob  = (bf16*)(ws + 84279296);   // [256][256]
  bf16* ebf  = (bf16*)(ws + 84410368);   // [64][128]
  bf16* fbf  = (bf16*)(ws + 84426752);   // [64][128]

  k_prep <<<768,  256, 0, stream>>>(wq, wk, wv, wo, E, F, wqkv, wob, ebf, fbf);
  k_ln1  <<<8192, 256, 0, stream>>>(tok, g1, b1, tn);
  k_qkv  <<<dim3(256, 3), 512, 0, stream>>>(tn, wqkv, Qn, kT, vT);
  k_kproj<<<256,  256, 0, stream>>>(kT, ebf, kp);
  k_vproj<<<256,  256, 0, stream>>>(vT, fbf, vpt);
  bf16*  attnP = kT;                     // [2][32768][256] over kT..vT (32MB contiguous, dead)
  float* denP  = (float*)tn;             // [2][32768] f32 (tn dead after k_qkv)
  k_attn <<<256,  512, 0, stream>>>(Qn, kp, vpt, sc, attnP, denP);
  k_outln<<<512,  256, 0, stream>>>(attnP, denP, wob, tok, g2, b2, out);
}